// Round 1
// baseline (873.150 us; speedup 1.0000x reference)
//
#include <hip/hip_runtime.h>
#include <cstdint>
#include <cstddef>

#define NN 100000
#define NE 1600000
#define HID 128
#define TILE_ROWS 32
#define SCAN_CHUNK 1024
#define NB_SCAN ((NN + SCAN_CHUNK - 1) / SCAN_CHUNK)   // 98

typedef unsigned int u32;

// ---------------- CSR build ----------------

__global__ __launch_bounds__(256) void count_kernel(const int* __restrict__ dst,
                                                    u32* __restrict__ deg) {
    int e = blockIdx.x * 256 + threadIdx.x;
    if (e < NE) atomicAdd(&deg[dst[e]], 1u);
}

__global__ __launch_bounds__(256) void scan1_kernel(const u32* __restrict__ deg,
                                                    u32* __restrict__ part) {
    __shared__ u32 s[256];
    int t = threadIdx.x;
    int base = blockIdx.x * SCAN_CHUNK + t * 4;
    u32 sum = 0;
#pragma unroll
    for (int i = 0; i < 4; i++) {
        int idx = base + i;
        if (idx < NN) sum += deg[idx];
    }
    s[t] = sum;
    __syncthreads();
#pragma unroll
    for (int off = 128; off > 0; off >>= 1) {
        if (t < off) s[t] += s[t + off];
        __syncthreads();
    }
    if (t == 0) part[blockIdx.x] = s[0];
}

__global__ void scan2_kernel(u32* part, u32* rs) {
    u32 run = 0;
    for (int b = 0; b < NB_SCAN; b++) {
        u32 v = part[b];
        part[b] = run;
        run += v;
    }
    rs[NN] = run;   // == NE
}

__global__ __launch_bounds__(256) void scan3_kernel(const u32* __restrict__ deg,
                                                    const u32* __restrict__ part,
                                                    u32* __restrict__ rs) {
    __shared__ u32 s[256];
    int t = threadIdx.x;
    int base = blockIdx.x * SCAN_CHUNK + t * 4;
    u32 v[4];
    u32 lsum = 0;
#pragma unroll
    for (int i = 0; i < 4; i++) {
        int idx = base + i;
        v[i] = (idx < NN) ? deg[idx] : 0u;
        lsum += v[i];
    }
    s[t] = lsum;
    __syncthreads();
    for (int off = 1; off < 256; off <<= 1) {
        u32 add = (t >= off) ? s[t - off] : 0u;
        __syncthreads();
        s[t] += add;
        __syncthreads();
    }
    u32 run = part[blockIdx.x] + s[t] - lsum;   // exclusive prefix
#pragma unroll
    for (int i = 0; i < 4; i++) {
        int idx = base + i;
        if (idx < NN) { rs[idx] = run; run += v[i]; }
    }
}

__global__ __launch_bounds__(256) void scatter_kernel(const int* __restrict__ src,
                                                      const int* __restrict__ dst,
                                                      const int* __restrict__ attr,
                                                      const u32* __restrict__ rs,
                                                      u32* __restrict__ cur,
                                                      u32* __restrict__ ep) {
    int e = blockIdx.x * 256 + threadIdx.x;
    if (e >= NE) return;
    int d = dst[e];
    u32 pos = atomicAdd(&cur[d], 1u);
    ep[rs[d] + pos] = (u32)src[e] | ((u32)attr[e] << 20);
}

// ---------------- aggregation: one wave per node ----------------
// agg[n] = sum over incoming edges of relu(h[src] + emb[attr]); pure writes, no zero-init needed.

__global__ __launch_bounds__(256) void agg_kernel(const float* __restrict__ h,
                                                  const u32* __restrict__ rs,
                                                  const u32* __restrict__ ep,
                                                  const float* __restrict__ emb,
                                                  float* __restrict__ agg) {
    __shared__ float semb[8 * HID];
    int tid = threadIdx.x;
    ((float4*)semb)[tid] = ((const float4*)emb)[tid];   // 256 f4 = 1024 floats
    __syncthreads();
    int wave = tid >> 6, lane = tid & 63;
    int node = blockIdx.x * 4 + wave;                   // 25000*4 == NN exactly
    u32 s0 = rs[node], s1 = rs[node + 1];
    const float2* h2 = (const float2*)h;
    const float2* e2 = (const float2*)semb;
    float ax = 0.f, ay = 0.f;
    u32 j = s0;
    // 2-way unroll for memory-level parallelism
    for (; j + 2 <= s1; j += 2) {
        u32 p0 = ep[j], p1 = ep[j + 1];
        float2 h0 = h2[(size_t)(p0 & 0xFFFFFu) * 64 + lane];
        float2 h1 = h2[(size_t)(p1 & 0xFFFFFu) * 64 + lane];
        float2 e0 = e2[(p0 >> 20) * 64 + lane];
        float2 e1 = e2[(p1 >> 20) * 64 + lane];
        ax += fmaxf(h0.x + e0.x, 0.f) + fmaxf(h1.x + e1.x, 0.f);
        ay += fmaxf(h0.y + e0.y, 0.f) + fmaxf(h1.y + e1.y, 0.f);
    }
    for (; j < s1; j++) {
        u32 p = ep[j];
        float2 hv = h2[(size_t)(p & 0xFFFFFu) * 64 + lane];
        float2 ev = e2[(p >> 20) * 64 + lane];
        ax += fmaxf(hv.x + ev.x, 0.f);
        ay += fmaxf(hv.y + ev.y, 0.f);
    }
    float2 o; o.x = ax; o.y = ay;
    ((float2*)agg)[(size_t)node * 64 + lane] = o;
}

// ---------------- fused node MLP ----------------
// out = relu(...relu(relu(A @ W0 + b0) @ W1 + b1)... ) with A = (GINE ? (1+eps)*in + agg : in)
// Row-local => in-place (out == in or out == agg) is safe.
// LDS: A[32][128] (16KB) + W[128][128] (64KB) = 80KB exactly -> 2 blocks/CU.

template <int NL, bool GINE>
__global__ __launch_bounds__(256, 2) void mlp_kernel(
    const float* __restrict__ in, const float* __restrict__ agg,
    const float* __restrict__ epsp, float* __restrict__ out,
    const float* __restrict__ W0, const float* __restrict__ b0,
    const float* __restrict__ W1, const float* __restrict__ b1,
    const float* __restrict__ W2, const float* __restrict__ b2) {
    __shared__ float As[TILE_ROWS][HID];
    __shared__ float Ws[HID][HID];
    int tid = threadIdx.x;
    int row0 = blockIdx.x * TILE_ROWS;
    float scale = 1.0f;
    if (GINE) scale += epsp[0];

    // stage A tile (32 rows x 128)
#pragma unroll
    for (int t = 0; t < 4; t++) {
        int idx = t * 256 + tid;
        int r = idx >> 5, c4 = (idx & 31) * 4;
        float4 v = *(const float4*)&in[(size_t)(row0 + r) * HID + c4];
        if (GINE) {
            float4 g = *(const float4*)&agg[(size_t)(row0 + r) * HID + c4];
            v.x = scale * v.x + g.x; v.y = scale * v.y + g.y;
            v.z = scale * v.z + g.z; v.w = scale * v.w + g.w;
        }
        *(float4*)&As[r][c4] = v;
    }
    // stage W0
#pragma unroll
    for (int t = 0; t < 16; t++) {
        int idx = t * 256 + tid;
        int r = idx >> 5, c4 = (idx & 31) * 4;
        *(float4*)&Ws[r][c4] = *(const float4*)&W0[r * HID + c4];
    }
    __syncthreads();

    int cg = tid & 31, rg = tid >> 5;
    int c0 = cg * 4, r0 = rg * 4;

#pragma unroll 1
    for (int l = 0; l < NL; l++) {
        const float* bl = (l == 0) ? b0 : ((l == 1) ? b1 : b2);
        float4 bv = *(const float4*)&bl[c0];
        float acc[4][4];
#pragma unroll
        for (int i = 0; i < 4; i++) {
            acc[i][0] = bv.x; acc[i][1] = bv.y; acc[i][2] = bv.z; acc[i][3] = bv.w;
        }
#pragma unroll 8
        for (int k = 0; k < HID; k += 4) {
            float a_[4][4], w_[4][4];
#pragma unroll
            for (int i = 0; i < 4; i++) {
                float4 v = *(const float4*)&As[r0 + i][k];   // wave-broadcast read
                a_[i][0] = v.x; a_[i][1] = v.y; a_[i][2] = v.z; a_[i][3] = v.w;
            }
#pragma unroll
            for (int kk = 0; kk < 4; kk++) {
                float4 v = *(const float4*)&Ws[k + kk][c0];  // full-row spread read
                w_[kk][0] = v.x; w_[kk][1] = v.y; w_[kk][2] = v.z; w_[kk][3] = v.w;
            }
#pragma unroll
            for (int i = 0; i < 4; i++)
#pragma unroll
                for (int kk = 0; kk < 4; kk++)
#pragma unroll
                    for (int j = 0; j < 4; j++)
                        acc[i][j] = fmaf(a_[i][kk], w_[kk][j], acc[i][j]);
        }
        __syncthreads();   // everyone done reading As / Ws
#pragma unroll
        for (int i = 0; i < 4; i++) {
            float4 v;
            v.x = fmaxf(acc[i][0], 0.f); v.y = fmaxf(acc[i][1], 0.f);
            v.z = fmaxf(acc[i][2], 0.f); v.w = fmaxf(acc[i][3], 0.f);
            *(float4*)&As[r0 + i][c0] = v;
        }
        if (l + 1 < NL) {
            const float* Wl = (l == 0) ? W1 : W2;
#pragma unroll
            for (int t = 0; t < 16; t++) {
                int idx = t * 256 + tid;
                int r = idx >> 5, c4 = (idx & 31) * 4;
                *(float4*)&Ws[r][c4] = *(const float4*)&Wl[r * HID + c4];
            }
        }
        __syncthreads();
    }

    // writeback
#pragma unroll
    for (int t = 0; t < 4; t++) {
        int idx = t * 256 + tid;
        int r = idx >> 5, c4 = (idx & 31) * 4;
        float4 v = *(const float4*)&As[r][c4];
        *(float4*)&out[(size_t)(row0 + r) * HID + c4] = v;
    }
}

// ---------------- launch ----------------

extern "C" void kernel_launch(void* const* d_in, const int* in_sizes, int n_in,
                              void* d_out, int out_size, void* d_ws, size_t ws_size,
                              hipStream_t stream) {
    const float* x    = (const float*)d_in[0];
    const int*   ei   = (const int*)d_in[1];      // [2, NE]
    const int*   ea   = (const int*)d_in[2];
    const float* Wx   = (const float*)d_in[3];
    const float* bx   = (const float*)d_in[4];
    const float* emb  = (const float*)d_in[5];
    const float* eps1 = (const float*)d_in[6];
    const float* eps2 = (const float*)d_in[7];
    const float* W1a = (const float*)d_in[8],  *b1a = (const float*)d_in[9];
    const float* W1b = (const float*)d_in[10], *b1b = (const float*)d_in[11];
    const float* W1c = (const float*)d_in[12], *b1c = (const float*)d_in[13];
    const float* W2a = (const float*)d_in[14], *b2a = (const float*)d_in[15];
    const float* W2b = (const float*)d_in[16], *b2b = (const float*)d_in[17];
    const float* W2c = (const float*)d_in[18], *b2c = (const float*)d_in[19];
    float* out = (float*)d_out;

    const int* srcp = ei;
    const int* dstp = ei + NE;

    // workspace layout (all 16B aligned)
    char* ws = (char*)d_ws;
    float* h   = (float*)ws;                          // NN*HID floats = 51,200,000 B
    size_t off = (size_t)NN * HID * sizeof(float);
    u32* deg  = (u32*)(ws + off); off += (size_t)NN * 4;          // 400,000
    u32* rs   = (u32*)(ws + off); off += 400016;                  // NN+1, padded
    u32* cur  = (u32*)(ws + off); off += (size_t)NN * 4;          // 400,000
    u32* part = (u32*)(ws + off); off += 512;                     // NB_SCAN
    u32* ep   = (u32*)(ws + off); off += (size_t)NE * 4;          // 6,400,000

    hipMemsetAsync(deg, 0, (size_t)NN * 4, stream);
    hipMemsetAsync(cur, 0, (size_t)NN * 4, stream);

    // h = relu(x @ Wx + bx)
    mlp_kernel<1, false><<<NN / TILE_ROWS, 256, 0, stream>>>(
        x, nullptr, nullptr, h, Wx, bx, nullptr, nullptr, nullptr, nullptr);

    // CSR build
    count_kernel<<<NE / 256, 256, 0, stream>>>(dstp, deg);
    scan1_kernel<<<NB_SCAN, 256, 0, stream>>>(deg, part);
    scan2_kernel<<<1, 1, 0, stream>>>(part, rs);
    scan3_kernel<<<NB_SCAN, 256, 0, stream>>>(deg, part, rs);
    scatter_kernel<<<NE / 256, 256, 0, stream>>>(srcp, dstp, ea, rs, cur, ep);

    // layer 1: agg (into d_out as scratch) then fused MLP, h updated in place
    agg_kernel<<<NN / 4, 256, 0, stream>>>(h, rs, ep, emb, out);
    mlp_kernel<3, true><<<NN / TILE_ROWS, 256, 0, stream>>>(
        h, out, eps1, h, W1a, b1a, W1b, b1b, W1c, b1c);

    // layer 2: agg then MLP, final result to d_out (row-local in-place over agg)
    agg_kernel<<<NN / 4, 256, 0, stream>>>(h, rs, ep, emb, out);
    mlp_kernel<3, true><<<NN / TILE_ROWS, 256, 0, stream>>>(
        h, out, eps2, out, W2a, b2a, W2b, b2b, W2c, b2c);
}

// Round 3
// 633.615 us; speedup vs baseline: 1.3780x; 1.3780x over previous
//
#include <hip/hip_runtime.h>
#include <hip/hip_bf16.h>
#include <cstdint>
#include <cstddef>

#define NN 100000
#define NNP 100096            // padded to 782*128
#define NE 1600000
#define HID 128
#define SCAN_CHUNK 1024
#define NB_SCAN 98

typedef unsigned int u32;
typedef unsigned short u16;
typedef __bf16 bf16x8 __attribute__((ext_vector_type(8)));
typedef float f32x16 __attribute__((ext_vector_type(16)));

__device__ inline u32 pack2(float a, float b) {
    u16 x = __builtin_bit_cast(u16, (__bf16)a);
    u16 y = __builtin_bit_cast(u16, (__bf16)b);
    return (u32)x | ((u32)y << 16);
}
__device__ inline float b2f(u16 v) { return __uint_as_float((u32)v << 16); }

// ---------------- CSR build ----------------

__global__ __launch_bounds__(256) void count_kernel(const int* __restrict__ dst,
                                                    u32* __restrict__ deg) {
    int e = blockIdx.x * 256 + threadIdx.x;
    if (e < NE) atomicAdd(&deg[dst[e]], 1u);
}

__global__ __launch_bounds__(256) void scan1_kernel(const u32* __restrict__ deg,
                                                    u32* __restrict__ part) {
    __shared__ u32 s[256];
    int t = threadIdx.x;
    int base = blockIdx.x * SCAN_CHUNK + t * 4;
    u32 sum = 0;
#pragma unroll
    for (int i = 0; i < 4; i++) {
        int idx = base + i;
        if (idx < NN) sum += deg[idx];
    }
    s[t] = sum;
    __syncthreads();
#pragma unroll
    for (int off = 128; off > 0; off >>= 1) {
        if (t < off) s[t] += s[t + off];
        __syncthreads();
    }
    if (t == 0) part[blockIdx.x] = s[0];
}

__global__ void scan2_kernel(u32* part, u32* rs) {
    u32 run = 0;
    for (int b = 0; b < NB_SCAN; b++) {
        u32 v = part[b];
        part[b] = run;
        run += v;
    }
    rs[NN] = run;
}

__global__ __launch_bounds__(256) void scan3_kernel(const u32* __restrict__ deg,
                                                    const u32* __restrict__ part,
                                                    u32* __restrict__ rs) {
    __shared__ u32 s[256];
    int t = threadIdx.x;
    int base = blockIdx.x * SCAN_CHUNK + t * 4;
    u32 v[4];
    u32 lsum = 0;
#pragma unroll
    for (int i = 0; i < 4; i++) {
        int idx = base + i;
        v[i] = (idx < NN) ? deg[idx] : 0u;
        lsum += v[i];
    }
    s[t] = lsum;
    __syncthreads();
    for (int off = 1; off < 256; off <<= 1) {
        u32 add = (t >= off) ? s[t - off] : 0u;
        __syncthreads();
        s[t] += add;
        __syncthreads();
    }
    u32 run = part[blockIdx.x] + s[t] - lsum;
#pragma unroll
    for (int i = 0; i < 4; i++) {
        int idx = base + i;
        if (idx < NN) { rs[idx] = run; run += v[i]; }
    }
}

__global__ __launch_bounds__(256) void scatter_kernel(const int* __restrict__ src,
                                                      const int* __restrict__ dst,
                                                      const int* __restrict__ attr,
                                                      const u32* __restrict__ rs,
                                                      u32* __restrict__ cur,
                                                      u32* __restrict__ ep) {
    int e = blockIdx.x * 256 + threadIdx.x;
    if (e >= NE) return;
    int d = dst[e];
    u32 pos = atomicAdd(&cur[d], 1u);
    ep[rs[d] + pos] = (u32)src[e] | ((u32)attr[e] << 20);
}

// ---------------- aggregation (bf16 h, bf16 agg) ----------------
// one wave per node; lane covers 2 feature cols (u32 = 2 bf16)

__global__ __launch_bounds__(256) void agg_kernel(const u16* __restrict__ h,
                                                  const u32* __restrict__ rs,
                                                  const u32* __restrict__ ep,
                                                  const float* __restrict__ emb,
                                                  u16* __restrict__ agg) {
    __shared__ float semb[8 * HID];
    int tid = threadIdx.x;
    ((float4*)semb)[tid] = ((const float4*)emb)[tid];
    __syncthreads();
    int wave = tid >> 6, lane = tid & 63;
    int node = blockIdx.x * 4 + wave;
    u32 s0 = rs[node], s1 = rs[node + 1];
    const u32* h32 = (const u32*)h;
    const float2* e2 = (const float2*)semb;
    float ax = 0.f, ay = 0.f;
    u32 j = s0;
    for (; j + 2 <= s1; j += 2) {
        u32 p0 = ep[j], p1 = ep[j + 1];
        u32 hv0 = h32[(size_t)(p0 & 0xFFFFFu) * 64 + lane];
        u32 hv1 = h32[(size_t)(p1 & 0xFFFFFu) * 64 + lane];
        float2 e0 = e2[(p0 >> 20) * 64 + lane];
        float2 e1 = e2[(p1 >> 20) * 64 + lane];
        ax += fmaxf(__uint_as_float(hv0 << 16) + e0.x, 0.f)
            + fmaxf(__uint_as_float(hv1 << 16) + e1.x, 0.f);
        ay += fmaxf(__uint_as_float(hv0 & 0xFFFF0000u) + e0.y, 0.f)
            + fmaxf(__uint_as_float(hv1 & 0xFFFF0000u) + e1.y, 0.f);
    }
    for (; j < s1; j++) {
        u32 p = ep[j];
        u32 hv = h32[(size_t)(p & 0xFFFFFu) * 64 + lane];
        float2 ev = e2[(p >> 20) * 64 + lane];
        ax += fmaxf(__uint_as_float(hv << 16) + ev.x, 0.f);
        ay += fmaxf(__uint_as_float(hv & 0xFFFF0000u) + ev.y, 0.f);
    }
    ((u32*)agg)[(size_t)node * 64 + lane] = pack2(ax, ay);
}

// ---------------- MFMA MLP ----------------
// tile 128 rows x 128 cols, 4 waves (256 thr), wave owns 32 rows.
// LDS: sA[128][128] bf16 swizzled (32KB) + sW = W^T [n][k] bf16 swizzled (32KB).
// swizzle: byte_in_row ^= (row&15)<<4  (bijective, kills row-major D=128 conflicts)

__device__ inline void stageW(char* sW, const float* __restrict__ W, int tid) {
#pragma unroll
    for (int it = 0; it < 8; ++it) {
        int u = it * 256 + tid;
        int kp = u >> 5, n4 = (u & 31) * 4;           // k-pair, 4 n's
        float4 w0 = *(const float4*)&W[(size_t)(2 * kp) * HID + n4];
        float4 w1 = *(const float4*)&W[(size_t)(2 * kp + 1) * HID + n4];
        float a0[4] = {w0.x, w0.y, w0.z, w0.w};
        float a1[4] = {w1.x, w1.y, w1.z, w1.w};
#pragma unroll
        for (int nn = 0; nn < 4; ++nn) {
            int n = n4 + nn;
            *(u32*)(sW + n * 256 + ((kp * 4) ^ ((n & 15) << 4))) = pack2(a0[nn], a1[nn]);
        }
    }
}

template <int NL, int MODE, bool OUTB>
__global__ __launch_bounds__(256, 2) void mlp_mfma(
    const void* __restrict__ inp, const u16* __restrict__ aggb,
    const float* __restrict__ epsp, void* __restrict__ outp,
    const float* __restrict__ W0, const float* __restrict__ b0,
    const float* __restrict__ W1, const float* __restrict__ b1,
    const float* __restrict__ W2, const float* __restrict__ b2) {
    __shared__ __align__(16) char sA[128 * 256];
    __shared__ __align__(16) char sW[128 * 256];
    int tid = threadIdx.x;
    int row0 = blockIdx.x * 128;

    // ---- stage A tile as bf16 (swizzled) ----
    if (MODE == 0) {
        const float* x = (const float*)inp;
#pragma unroll
        for (int it = 0; it < 16; ++it) {
            int idx = it * 256 + tid;
            int r = idx >> 5, c4 = (idx & 31) * 4;
            int grow = row0 + r;
            uint2 pk = make_uint2(0u, 0u);
            if (grow < NN) {
                float4 v = *(const float4*)&x[(size_t)grow * HID + c4];
                pk.x = pack2(v.x, v.y);
                pk.y = pack2(v.z, v.w);
            }
            *(uint2*)(sA + r * 256 + ((c4 * 2) ^ ((r & 15) << 4))) = pk;
        }
    } else {
        const u16* hin = (const u16*)inp;
        float eps = 1.0f + epsp[0];
#pragma unroll
        for (int it = 0; it < 16; ++it) {
            int idx = it * 256 + tid;
            int r = idx >> 5, c4 = (idx & 31) * 4;
            int grow = row0 + r;
            uint2 pk = make_uint2(0u, 0u);
            if (grow < NN) {
                ushort4 hv = *(const ushort4*)&hin[(size_t)grow * HID + c4];
                ushort4 gv = *(const ushort4*)&aggb[(size_t)grow * HID + c4];
                pk.x = pack2(eps * b2f(hv.x) + b2f(gv.x), eps * b2f(hv.y) + b2f(gv.y));
                pk.y = pack2(eps * b2f(hv.z) + b2f(gv.z), eps * b2f(hv.w) + b2f(gv.w));
            }
            *(uint2*)(sA + r * 256 + ((c4 * 2) ^ ((r & 15) << 4))) = pk;
        }
    }
    stageW(sW, W0, tid);
    __syncthreads();

    int lane = tid & 63, w = tid >> 6;
    int lo5 = lane & 31, hi = lane >> 5;
    int swzkey = (lo5 & 15) << 4;

#pragma unroll 1
    for (int l = 0; l < NL; ++l) {
        const float* bl = (l == 0) ? b0 : ((l == 1) ? b1 : b2);
        f32x16 acc[4];
#pragma unroll
        for (int nf = 0; nf < 4; ++nf) {
            float bv = bl[nf * 32 + lo5];
#pragma unroll
            for (int i = 0; i < 16; ++i) acc[nf][i] = bv;
        }
#pragma unroll
        for (int kc = 0; kc < 8; ++kc) {
            int koff = kc * 32 + hi * 16;
            bf16x8 a = *(const bf16x8*)(sA + (32 * w + lo5) * 256 + (koff ^ swzkey));
#pragma unroll
            for (int nf = 0; nf < 4; ++nf) {
                bf16x8 bb = *(const bf16x8*)(sW + (nf * 32 + lo5) * 256 + (koff ^ swzkey));
                acc[nf] = __builtin_amdgcn_mfma_f32_32x32x16_bf16(a, bb, acc[nf], 0, 0, 0);
            }
        }
        if (l + 1 < NL) {
            __syncthreads();                       // all waves done reading sA/sW
            stageW(sW, (l == 0) ? W1 : W2, tid);   // next layer's W^T
            // write relu(C) back to sA as next A (bf16, swizzled)
#pragma unroll
            for (int nf = 0; nf < 4; ++nf) {
#pragma unroll
                for (int reg = 0; reg < 16; ++reg) {
                    int r32 = (reg & 3) + 8 * (reg >> 2) + 4 * hi;
                    int col = nf * 32 + lo5;
                    float v = fmaxf(acc[nf][reg], 0.f);
                    *(u16*)(sA + (32 * w + r32) * 256 + ((col * 2) ^ ((r32 & 15) << 4))) =
                        __builtin_bit_cast(u16, (__bf16)v);
                }
            }
            __syncthreads();
        } else {
            // final layer of this kernel: relu + global write
#pragma unroll
            for (int nf = 0; nf < 4; ++nf) {
#pragma unroll
                for (int reg = 0; reg < 16; ++reg) {
                    int r32 = (reg & 3) + 8 * (reg >> 2) + 4 * hi;
                    int grow = row0 + 32 * w + r32;
                    int col = nf * 32 + lo5;
                    float v = fmaxf(acc[nf][reg], 0.f);
                    if (grow < NN) {
                        if (OUTB)
                            ((u16*)outp)[(size_t)grow * HID + col] =
                                __builtin_bit_cast(u16, (__bf16)v);
                        else
                            ((float*)outp)[(size_t)grow * HID + col] = v;
                    }
                }
            }
        }
    }
}

// ---------------- launch ----------------

extern "C" void kernel_launch(void* const* d_in, const int* in_sizes, int n_in,
                              void* d_out, int out_size, void* d_ws, size_t ws_size,
                              hipStream_t stream) {
    const float* x    = (const float*)d_in[0];
    const int*   ei   = (const int*)d_in[1];
    const int*   ea   = (const int*)d_in[2];
    const float* Wx   = (const float*)d_in[3];
    const float* bx   = (const float*)d_in[4];
    const float* emb  = (const float*)d_in[5];
    const float* eps1 = (const float*)d_in[6];
    const float* eps2 = (const float*)d_in[7];
    const float* W1a = (const float*)d_in[8],  *b1a = (const float*)d_in[9];
    const float* W1b = (const float*)d_in[10], *b1b = (const float*)d_in[11];
    const float* W1c = (const float*)d_in[12], *b1c = (const float*)d_in[13];
    const float* W2a = (const float*)d_in[14], *b2a = (const float*)d_in[15];
    const float* W2b = (const float*)d_in[16], *b2b = (const float*)d_in[17];
    const float* W2c = (const float*)d_in[18], *b2c = (const float*)d_in[19];
    float* out = (float*)d_out;

    const int* srcp = ei;
    const int* dstp = ei + NE;

    char* ws = (char*)d_ws;
    u16* h16  = (u16*)ws;                                   // NNP*128 bf16 = 25.6MB
    size_t off = (size_t)NNP * HID * 2;
    u16* agg16 = (u16*)(ws + off); off += (size_t)NNP * HID * 2;   // 25.6MB
    u32* deg  = (u32*)(ws + off); off += (size_t)NN * 4;
    u32* rs   = (u32*)(ws + off); off += 400032;
    u32* cur  = (u32*)(ws + off); off += (size_t)NN * 4;
    u32* part = (u32*)(ws + off); off += 512;
    u32* ep   = (u32*)(ws + off); off += (size_t)NE * 4;

    hipMemsetAsync(deg, 0, (size_t)NN * 4, stream);
    hipMemsetAsync(cur, 0, (size_t)NN * 4, stream);

    // h = relu(x @ Wx + bx)  -> bf16
    mlp_mfma<1, 0, true><<<NNP / 128, 256, 0, stream>>>(
        x, nullptr, nullptr, h16, Wx, bx, nullptr, nullptr, nullptr, nullptr);

    // CSR build
    count_kernel<<<NE / 256, 256, 0, stream>>>(dstp, deg);
    scan1_kernel<<<NB_SCAN, 256, 0, stream>>>(deg, part);
    scan2_kernel<<<1, 1, 0, stream>>>(part, rs);
    scan3_kernel<<<NB_SCAN, 256, 0, stream>>>(deg, part, rs);
    scatter_kernel<<<NE / 256, 256, 0, stream>>>(srcp, dstp, ea, rs, cur, ep);

    // layer 1
    agg_kernel<<<NN / 4, 256, 0, stream>>>(h16, rs, ep, emb, agg16);
    mlp_mfma<3, 1, true><<<NNP / 128, 256, 0, stream>>>(
        h16, agg16, eps1, h16, W1a, b1a, W1b, b1b, W1c, b1c);

    // layer 2 -> d_out fp32
    agg_kernel<<<NN / 4, 256, 0, stream>>>(h16, rs, ep, emb, agg16);
    mlp_mfma<3, 1, false><<<NNP / 128, 256, 0, stream>>>(
        h16, agg16, eps2, out, W2a, b2a, W2b, b2b, W2c, b2c);
}

// Round 4
// 528.736 us; speedup vs baseline: 1.6514x; 1.1984x over previous
//
#include <hip/hip_runtime.h>
#include <hip/hip_bf16.h>
#include <cstdint>
#include <cstddef>

#define NN 100000
#define NNP 100096            // padded to 782*128
#define NE 1600000
#define HID 128
#define SCAN_CHUNK 1024
#define NB_SCAN 98

typedef unsigned int u32;
typedef unsigned short u16;
typedef __bf16 bf16x8 __attribute__((ext_vector_type(8)));
typedef float f32x16 __attribute__((ext_vector_type(16)));

__device__ inline u32 pack2(float a, float b) {
    u16 x = __builtin_bit_cast(u16, (__bf16)a);
    u16 y = __builtin_bit_cast(u16, (__bf16)b);
    return (u32)x | ((u32)y << 16);
}
__device__ inline float b2f(u16 v) { return __uint_as_float((u32)v << 16); }

// ---------------- CSR build ----------------

__global__ __launch_bounds__(256) void count_kernel(const int* __restrict__ dst,
                                                    u32* __restrict__ deg) {
    int e = blockIdx.x * 256 + threadIdx.x;
    if (e < NE) atomicAdd(&deg[dst[e]], 1u);
}

__global__ __launch_bounds__(256) void scan1_kernel(const u32* __restrict__ deg,
                                                    u32* __restrict__ part) {
    __shared__ u32 s[256];
    int t = threadIdx.x;
    int base = blockIdx.x * SCAN_CHUNK + t * 4;
    u32 sum = 0;
#pragma unroll
    for (int i = 0; i < 4; i++) {
        int idx = base + i;
        if (idx < NN) sum += deg[idx];
    }
    s[t] = sum;
    __syncthreads();
#pragma unroll
    for (int off = 128; off > 0; off >>= 1) {
        if (t < off) s[t] += s[t + off];
        __syncthreads();
    }
    if (t == 0) part[blockIdx.x] = s[0];
}

__global__ void scan2_kernel(u32* part, u32* rs) {
    u32 run = 0;
    for (int b = 0; b < NB_SCAN; b++) {
        u32 v = part[b];
        part[b] = run;
        run += v;
    }
    rs[NN] = run;
}

__global__ __launch_bounds__(256) void scan3_kernel(const u32* __restrict__ deg,
                                                    const u32* __restrict__ part,
                                                    u32* __restrict__ rs) {
    __shared__ u32 s[256];
    int t = threadIdx.x;
    int base = blockIdx.x * SCAN_CHUNK + t * 4;
    u32 v[4];
    u32 lsum = 0;
#pragma unroll
    for (int i = 0; i < 4; i++) {
        int idx = base + i;
        v[i] = (idx < NN) ? deg[idx] : 0u;
        lsum += v[i];
    }
    s[t] = lsum;
    __syncthreads();
    for (int off = 1; off < 256; off <<= 1) {
        u32 add = (t >= off) ? s[t - off] : 0u;
        __syncthreads();
        s[t] += add;
        __syncthreads();
    }
    u32 run = part[blockIdx.x] + s[t] - lsum;
#pragma unroll
    for (int i = 0; i < 4; i++) {
        int idx = base + i;
        if (idx < NN) { rs[idx] = run; run += v[i]; }
    }
}

__global__ __launch_bounds__(256) void scatter_kernel(const int* __restrict__ src,
                                                      const int* __restrict__ dst,
                                                      const int* __restrict__ attr,
                                                      const u32* __restrict__ rs,
                                                      u32* __restrict__ cur,
                                                      u32* __restrict__ ep) {
    int e = blockIdx.x * 256 + threadIdx.x;
    if (e >= NE) return;
    int d = dst[e];
    u32 pos = atomicAdd(&cur[d], 1u);
    ep[rs[d] + pos] = (u32)src[e] | ((u32)attr[e] << 20);
}

// ---------------- W pre-transpose: W[k][n] fp32 -> Wt[n][k] bf16 ----------------
// grid = 14 blocks: block (m, half); LDS-staged, padded to kill column-read conflicts.

__global__ __launch_bounds__(256) void wt_kernel(const float* __restrict__ W0,
                                                 const float* __restrict__ W1,
                                                 const float* __restrict__ W2,
                                                 const float* __restrict__ W3,
                                                 const float* __restrict__ W4,
                                                 const float* __restrict__ W5,
                                                 const float* __restrict__ W6,
                                                 u32* __restrict__ Wt) {
    __shared__ float s[64][129];
    int m = blockIdx.x >> 1, h = blockIdx.x & 1;
    const float* W = (m == 0) ? W0 : (m == 1) ? W1 : (m == 2) ? W2 : (m == 3) ? W3
                   : (m == 4) ? W4 : (m == 5) ? W5 : W6;
    int tid = threadIdx.x;
    // stage rows [64h, 64h+64) coalesced
#pragma unroll
    for (int it = 0; it < 8; ++it) {
        int u = it * 256 + tid;
        int r = u >> 5, c4 = (u & 31) * 4;
        float4 v = *(const float4*)&W[(size_t)(64 * h + r) * HID + c4];
        s[r][c4] = v.x; s[r][c4 + 1] = v.y; s[r][c4 + 2] = v.z; s[r][c4 + 3] = v.w;
    }
    __syncthreads();
    // write Wt[n][kp] u32 (2 bf16), kp in [32h, 32h+32)
    u32* outm = Wt + (size_t)m * 8192;
#pragma unroll
    for (int it = 0; it < 16; ++it) {
        int u = it * 256 + tid;
        int n = u >> 5, kpl = u & 31;
        u32 v = pack2(s[2 * kpl][n], s[2 * kpl + 1][n]);
        outm[(size_t)n * 64 + 32 * h + kpl] = v;
    }
}

// ---------------- aggregation (bf16 h, bf16 agg) ----------------
// one wave per node; lane covers 2 feature cols; 8-deep gather batching for MLP.

__global__ __launch_bounds__(256) void agg_kernel(const u16* __restrict__ h,
                                                  const u32* __restrict__ rs,
                                                  const u32* __restrict__ ep,
                                                  const float* __restrict__ emb,
                                                  u16* __restrict__ agg) {
    __shared__ float semb[8 * HID];
    int tid = threadIdx.x;
    ((float4*)semb)[tid] = ((const float4*)emb)[tid];
    __syncthreads();
    int wave = tid >> 6, lane = tid & 63;
    int node = blockIdx.x * 4 + wave;
    u32 s0 = rs[node], s1 = rs[node + 1];
    const u32* h32 = (const u32*)h;
    const float2* e2 = (const float2*)semb;
    float ax = 0.f, ay = 0.f;
    u32 j = s0;
    for (; j + 8 <= s1; j += 8) {
        u32 p[8];
#pragma unroll
        for (int t = 0; t < 8; ++t) p[t] = ep[j + t];
        u32 hv[8];
#pragma unroll
        for (int t = 0; t < 8; ++t) hv[t] = h32[(size_t)(p[t] & 0xFFFFFu) * 64 + lane];
        float2 ev[8];
#pragma unroll
        for (int t = 0; t < 8; ++t) ev[t] = e2[(p[t] >> 20) * 64 + lane];
#pragma unroll
        for (int t = 0; t < 8; ++t) {
            ax += fmaxf(__uint_as_float(hv[t] << 16) + ev[t].x, 0.f);
            ay += fmaxf(__uint_as_float(hv[t] & 0xFFFF0000u) + ev[t].y, 0.f);
        }
    }
    if (j + 4 <= s1) {
        u32 p[4];
#pragma unroll
        for (int t = 0; t < 4; ++t) p[t] = ep[j + t];
        u32 hv[4];
#pragma unroll
        for (int t = 0; t < 4; ++t) hv[t] = h32[(size_t)(p[t] & 0xFFFFFu) * 64 + lane];
        float2 ev[4];
#pragma unroll
        for (int t = 0; t < 4; ++t) ev[t] = e2[(p[t] >> 20) * 64 + lane];
#pragma unroll
        for (int t = 0; t < 4; ++t) {
            ax += fmaxf(__uint_as_float(hv[t] << 16) + ev[t].x, 0.f);
            ay += fmaxf(__uint_as_float(hv[t] & 0xFFFF0000u) + ev[t].y, 0.f);
        }
        j += 4;
    }
    for (; j < s1; j++) {
        u32 p = ep[j];
        u32 hv = h32[(size_t)(p & 0xFFFFFu) * 64 + lane];
        float2 ev = e2[(p >> 20) * 64 + lane];
        ax += fmaxf(__uint_as_float(hv << 16) + ev.x, 0.f);
        ay += fmaxf(__uint_as_float(hv & 0xFFFF0000u) + ev.y, 0.f);
    }
    ((u32*)agg)[(size_t)node * 64 + lane] = pack2(ax, ay);
}

// ---------------- MFMA MLP ----------------
// tile 128 rows x 128 cols, 4 waves, wave owns 32 rows.
// LDS: sA[128 rows][256B] bf16 swizzled + sW = Wt rows [n][256B] bf16 swizzled.
// swizzle: byte_in_row ^= (row&15)<<4. W staged from pre-transposed bf16 Wt[n][k]
// via coalesced uint4 loads + uniform-bank b128 LDS writes (no scatter conflicts).

__device__ inline void stageWt(char* sW, const uint4* __restrict__ Wt4, int tid) {
#pragma unroll
    for (int it = 0; it < 8; ++it) {
        int u = it * 256 + tid;
        int n = u >> 4, c = u & 15;                 // 16 x 16B chunks per 256B row
        uint4 v = Wt4[(size_t)n * 16 + c];          // coalesced
        *(uint4*)(sW + n * 256 + ((c * 16) ^ ((n & 15) << 4))) = v;
    }
}

template <int NL, int MODE, bool OUTB>
__global__ __launch_bounds__(256, 2) void mlp_mfma(
    const void* __restrict__ inp, const u16* __restrict__ aggb,
    const float* __restrict__ epsp, void* __restrict__ outp,
    const u32* __restrict__ Wt0, const float* __restrict__ b0,
    const u32* __restrict__ Wt1, const float* __restrict__ b1,
    const u32* __restrict__ Wt2, const float* __restrict__ b2) {
    __shared__ __align__(16) char sA[128 * 256];
    __shared__ __align__(16) char sW[128 * 256];
    int tid = threadIdx.x;
    int row0 = blockIdx.x * 128;

    // ---- stage A tile as bf16 (swizzled) ----
    if (MODE == 0) {
        const float* x = (const float*)inp;
#pragma unroll
        for (int it = 0; it < 16; ++it) {
            int idx = it * 256 + tid;
            int r = idx >> 5, c4 = (idx & 31) * 4;
            int grow = row0 + r;
            uint2 pk = make_uint2(0u, 0u);
            if (grow < NN) {
                float4 v = *(const float4*)&x[(size_t)grow * HID + c4];
                pk.x = pack2(v.x, v.y);
                pk.y = pack2(v.z, v.w);
            }
            *(uint2*)(sA + r * 256 + ((c4 * 2) ^ ((r & 15) << 4))) = pk;
        }
    } else {
        const u16* hin = (const u16*)inp;
        float eps = 1.0f + epsp[0];
#pragma unroll
        for (int it = 0; it < 16; ++it) {
            int idx = it * 256 + tid;
            int r = idx >> 5, c4 = (idx & 31) * 4;
            int grow = row0 + r;
            uint2 pk = make_uint2(0u, 0u);
            if (grow < NN) {
                ushort4 hv = *(const ushort4*)&hin[(size_t)grow * HID + c4];
                ushort4 gv = *(const ushort4*)&aggb[(size_t)grow * HID + c4];
                pk.x = pack2(eps * b2f(hv.x) + b2f(gv.x), eps * b2f(hv.y) + b2f(gv.y));
                pk.y = pack2(eps * b2f(hv.z) + b2f(gv.z), eps * b2f(hv.w) + b2f(gv.w));
            }
            *(uint2*)(sA + r * 256 + ((c4 * 2) ^ ((r & 15) << 4))) = pk;
        }
    }
    stageWt(sW, (const uint4*)Wt0, tid);
    __syncthreads();

    int lane = tid & 63, w = tid >> 6;
    int lo5 = lane & 31, hi = lane >> 5;
    int swzkey = (lo5 & 15) << 4;

#pragma unroll 1
    for (int l = 0; l < NL; ++l) {
        const float* bl = (l == 0) ? b0 : ((l == 1) ? b1 : b2);
        f32x16 acc[4];
#pragma unroll
        for (int nf = 0; nf < 4; ++nf) {
            float bv = bl[nf * 32 + lo5];
#pragma unroll
            for (int i = 0; i < 16; ++i) acc[nf][i] = bv;
        }
#pragma unroll
        for (int kc = 0; kc < 8; ++kc) {
            int koff = kc * 32 + hi * 16;
            bf16x8 a = *(const bf16x8*)(sA + (32 * w + lo5) * 256 + (koff ^ swzkey));
#pragma unroll
            for (int nf = 0; nf < 4; ++nf) {
                bf16x8 bb = *(const bf16x8*)(sW + (nf * 32 + lo5) * 256 + (koff ^ swzkey));
                acc[nf] = __builtin_amdgcn_mfma_f32_32x32x16_bf16(a, bb, acc[nf], 0, 0, 0);
            }
        }
        if (l + 1 < NL) {
            __syncthreads();                              // all waves done reading sA/sW
            stageWt(sW, (const uint4*)((l == 0) ? Wt1 : Wt2), tid);
            // write relu(C) back to sA as next A (bf16, swizzled)
#pragma unroll
            for (int nf = 0; nf < 4; ++nf) {
#pragma unroll
                for (int reg = 0; reg < 16; ++reg) {
                    int r32 = (reg & 3) + 8 * (reg >> 2) + 4 * hi;
                    int col = nf * 32 + lo5;
                    float v = fmaxf(acc[nf][reg], 0.f);
                    *(u16*)(sA + (32 * w + r32) * 256 + ((col * 2) ^ ((r32 & 15) << 4))) =
                        __builtin_bit_cast(u16, (__bf16)v);
                }
            }
            __syncthreads();
        } else {
            // final layer of this kernel: relu + global write
#pragma unroll
            for (int nf = 0; nf < 4; ++nf) {
#pragma unroll
                for (int reg = 0; reg < 16; ++reg) {
                    int r32 = (reg & 3) + 8 * (reg >> 2) + 4 * hi;
                    int grow = row0 + 32 * w + r32;
                    int col = nf * 32 + lo5;
                    float v = fmaxf(acc[nf][reg], 0.f);
                    if (grow < NN) {
                        if (OUTB)
                            ((u16*)outp)[(size_t)grow * HID + col] =
                                __builtin_bit_cast(u16, (__bf16)v);
                        else
                            ((float*)outp)[(size_t)grow * HID + col] = v;
                    }
                }
            }
        }
    }
}

// ---------------- launch ----------------

extern "C" void kernel_launch(void* const* d_in, const int* in_sizes, int n_in,
                              void* d_out, int out_size, void* d_ws, size_t ws_size,
                              hipStream_t stream) {
    const float* x    = (const float*)d_in[0];
    const int*   ei   = (const int*)d_in[1];
    const int*   ea   = (const int*)d_in[2];
    const float* Wx   = (const float*)d_in[3];
    const float* bx   = (const float*)d_in[4];
    const float* emb  = (const float*)d_in[5];
    const float* eps1 = (const float*)d_in[6];
    const float* eps2 = (const float*)d_in[7];
    const float* W1a = (const float*)d_in[8],  *b1a = (const float*)d_in[9];
    const float* W1b = (const float*)d_in[10], *b1b = (const float*)d_in[11];
    const float* W1c = (const float*)d_in[12], *b1c = (const float*)d_in[13];
    const float* W2a = (const float*)d_in[14], *b2a = (const float*)d_in[15];
    const float* W2b = (const float*)d_in[16], *b2b = (const float*)d_in[17];
    const float* W2c = (const float*)d_in[18], *b2c = (const float*)d_in[19];
    float* out = (float*)d_out;

    const int* srcp = ei;
    const int* dstp = ei + NE;

    char* ws = (char*)d_ws;
    u16* h16  = (u16*)ws;                                   // NNP*128 bf16 = 25.6MB
    size_t off = (size_t)NNP * HID * 2;
    u16* agg16 = (u16*)(ws + off); off += (size_t)NNP * HID * 2;   // 25.6MB
    u32* deg  = (u32*)(ws + off); off += (size_t)NN * 4;
    u32* rs   = (u32*)(ws + off); off += 400032;
    u32* cur  = (u32*)(ws + off); off += (size_t)NN * 4;
    u32* part = (u32*)(ws + off); off += 512;
    u32* ep   = (u32*)(ws + off); off += (size_t)NE * 4;
    u32* Wt   = (u32*)(ws + off); off += 7 * 8192 * 4;      // 7 x [128][64] u32

    hipMemsetAsync(deg, 0, (size_t)NN * 4, stream);
    hipMemsetAsync(cur, 0, (size_t)NN * 4, stream);

    // pre-transpose all 7 weight matrices to bf16 Wt[n][k]
    wt_kernel<<<14, 256, 0, stream>>>(Wx, W1a, W1b, W1c, W2a, W2b, W2c, Wt);

    // h = relu(x @ Wx + bx)  -> bf16
    mlp_mfma<1, 0, true><<<NNP / 128, 256, 0, stream>>>(
        x, nullptr, nullptr, h16, Wt, bx, nullptr, nullptr, nullptr, nullptr);

    // CSR build
    count_kernel<<<NE / 256, 256, 0, stream>>>(dstp, deg);
    scan1_kernel<<<NB_SCAN, 256, 0, stream>>>(deg, part);
    scan2_kernel<<<1, 1, 0, stream>>>(part, rs);
    scan3_kernel<<<NB_SCAN, 256, 0, stream>>>(deg, part, rs);
    scatter_kernel<<<NE / 256, 256, 0, stream>>>(srcp, dstp, ea, rs, cur, ep);

    // layer 1
    agg_kernel<<<NN / 4, 256, 0, stream>>>(h16, rs, ep, emb, agg16);
    mlp_mfma<3, 1, true><<<NNP / 128, 256, 0, stream>>>(
        h16, agg16, eps1, h16, Wt + 8192, b1a, Wt + 2 * 8192, b1b, Wt + 3 * 8192, b1c);

    // layer 2 -> d_out fp32
    agg_kernel<<<NN / 4, 256, 0, stream>>>(h16, rs, ep, emb, agg16);
    mlp_mfma<3, 1, false><<<NNP / 128, 256, 0, stream>>>(
        h16, agg16, eps2, out, Wt + 4 * 8192, b2a, Wt + 5 * 8192, b2b, Wt + 6 * 8192, b2c);
}

// Round 5
// 448.138 us; speedup vs baseline: 1.9484x; 1.1798x over previous
//
#include <hip/hip_runtime.h>
#include <hip/hip_bf16.h>
#include <cstdint>
#include <cstddef>

#define NN 100000
#define NNP 100096            // padded to 782*128
#define NE 1600000
#define HID 128
#define NBUK 196              // ceil(NN/512) buckets of 512 nodes
#define NBB 391               // ceil(NE/4096) edge blocks
#define ECH 4096              // edges per block in bin passes

typedef unsigned int u32;
typedef unsigned short u16;
typedef __bf16 bf16x8 __attribute__((ext_vector_type(8)));
typedef float f32x16 __attribute__((ext_vector_type(16)));

__device__ inline u32 pack2(float a, float b) {
    u16 x = __builtin_bit_cast(u16, (__bf16)a);
    u16 y = __builtin_bit_cast(u16, (__bf16)b);
    return (u32)x | ((u32)y << 16);
}
__device__ inline float b2f(u16 v) { return __uint_as_float((u32)v << 16); }

// ---------------- CSR build: two-level counting sort ----------------

// pass 1: bucket histogram (block-local LDS, then global add)
__global__ __launch_bounds__(256) void bincount_kernel(const int* __restrict__ dst,
                                                       u32* __restrict__ bcnt) {
    __shared__ u32 lh[256];
    int tid = threadIdx.x;
    lh[tid] = 0;
    __syncthreads();
    int e0 = blockIdx.x * ECH;
    for (int i = tid; i < ECH; i += 256) {
        int e = e0 + i;
        if (e < NE) atomicAdd(&lh[(u32)dst[e] >> 9], 1u);
    }
    __syncthreads();
    if (tid < NBUK && lh[tid]) atomicAdd(&bcnt[tid], lh[tid]);
}

// pass 2: exclusive scan of bucket counts -> boff[0..NBUK], bcur copy
__global__ __launch_bounds__(256) void bucketscan_kernel(const u32* __restrict__ bcnt,
                                                         u32* __restrict__ boff,
                                                         u32* __restrict__ bcur) {
    __shared__ u32 s[256];
    int t = threadIdx.x;
    u32 c = (t < NBUK) ? bcnt[t] : 0u;
    s[t] = c;
    __syncthreads();
    for (int off = 1; off < 256; off <<= 1) {
        u32 add = (t >= off) ? s[t - off] : 0u;
        __syncthreads();
        s[t] += add;
        __syncthreads();
    }
    u32 excl = s[t] - c;
    if (t <= NBUK) boff[t] = excl;
    if (t < NBUK) bcur[t] = excl;
}

// pass 3: partition edges into bucket regions (contiguous runs per block)
__global__ __launch_bounds__(256) void binscatter_kernel(const int* __restrict__ src,
                                                         const int* __restrict__ dst,
                                                         const int* __restrict__ attr,
                                                         u32* __restrict__ bcur,
                                                         u32* __restrict__ binned) {
    __shared__ u32 lh[256], rb[256], rc[256];
    int tid = threadIdx.x;
    lh[tid] = 0; rc[tid] = 0;
    __syncthreads();
    int e0 = blockIdx.x * ECH;
    for (int i = tid; i < ECH; i += 256) {
        int e = e0 + i;
        if (e < NE) atomicAdd(&lh[(u32)dst[e] >> 9], 1u);
    }
    __syncthreads();
    if (tid < NBUK && lh[tid]) rb[tid] = atomicAdd(&bcur[tid], lh[tid]);
    __syncthreads();
    for (int i = tid; i < ECH; i += 256) {
        int e = e0 + i;
        if (e < NE) {
            u32 d = (u32)dst[e];
            u32 b = d >> 9;
            u32 pos = rb[b] + atomicAdd(&rc[b], 1u);
            binned[pos] = (d & 511u) | ((u32)src[e] << 9) | ((u32)attr[e] << 26);
        }
    }
}

// pass 4: per-bucket node-level CSR (rs + ep), all within a 32KB window
__global__ __launch_bounds__(256) void bucketcsr_kernel(const u32* __restrict__ boff,
                                                        const u32* __restrict__ binned,
                                                        u32* __restrict__ rs,
                                                        u32* __restrict__ ep) {
    __shared__ u32 hist[512];
    __shared__ u32 s[256];
    int tid = threadIdx.x;
    int buk = blockIdx.x;
    u32 base = boff[buk], cnt = boff[buk + 1] - base;
    int n0 = buk << 9;
    int nloc = (NN - n0 < 512) ? (NN - n0) : 512;
    hist[tid] = 0; hist[tid + 256] = 0;
    __syncthreads();
    for (u32 i = tid; i < cnt; i += 256)
        atomicAdd(&hist[binned[base + i] & 511u], 1u);
    __syncthreads();
    // 512-wide exclusive scan (2 elems/thread)
    u32 v0 = hist[2 * tid], v1 = hist[2 * tid + 1];
    u32 ls = v0 + v1;
    s[tid] = ls;
    __syncthreads();
    for (int off = 1; off < 256; off <<= 1) {
        u32 add = (tid >= off) ? s[tid - off] : 0u;
        __syncthreads();
        s[tid] += add;
        __syncthreads();
    }
    u32 excl = s[tid] - ls;
    hist[2 * tid] = excl;
    hist[2 * tid + 1] = excl + v0;
    __syncthreads();
    // write rs (coalesced)
    if (tid < nloc) rs[n0 + tid] = base + hist[tid];
    for (int j = tid + 256; j < nloc; j += 256) rs[n0 + j] = base + hist[j];
    if (buk == NBUK - 1 && tid == 0) rs[NN] = base + cnt;
    __syncthreads();
    // scatter into final CSR order within the bucket window
    for (u32 i = tid; i < cnt; i += 256) {
        u32 v = binned[base + i];
        u32 dl = v & 511u;
        u32 pos = atomicAdd(&hist[dl], 1u);
        ep[base + pos] = ((v >> 9) & 0x1FFFFu) | ((v >> 26) << 20);
    }
}

// ---------------- W pre-transpose: W[k][n] fp32 -> Wt[n][k] bf16 ----------------

__global__ __launch_bounds__(256) void wt_kernel(const float* __restrict__ W0,
                                                 const float* __restrict__ W1,
                                                 const float* __restrict__ W2,
                                                 const float* __restrict__ W3,
                                                 const float* __restrict__ W4,
                                                 const float* __restrict__ W5,
                                                 const float* __restrict__ W6,
                                                 u32* __restrict__ Wt) {
    __shared__ float s[64][129];
    int m = blockIdx.x >> 1, h = blockIdx.x & 1;
    const float* W = (m == 0) ? W0 : (m == 1) ? W1 : (m == 2) ? W2 : (m == 3) ? W3
                   : (m == 4) ? W4 : (m == 5) ? W5 : W6;
    int tid = threadIdx.x;
#pragma unroll
    for (int it = 0; it < 8; ++it) {
        int u = it * 256 + tid;
        int r = u >> 5, c4 = (u & 31) * 4;
        float4 v = *(const float4*)&W[(size_t)(64 * h + r) * HID + c4];
        s[r][c4] = v.x; s[r][c4 + 1] = v.y; s[r][c4 + 2] = v.z; s[r][c4 + 3] = v.w;
    }
    __syncthreads();
    u32* outm = Wt + (size_t)m * 8192;
#pragma unroll
    for (int it = 0; it < 16; ++it) {
        int u = it * 256 + tid;
        int n = u >> 5, kpl = u & 31;
        u32 v = pack2(s[2 * kpl][n], s[2 * kpl + 1][n]);
        outm[(size_t)n * 64 + 32 * h + kpl] = v;
    }
}

// ---------------- aggregation (bf16 h, bf16 agg) ----------------

__global__ __launch_bounds__(256) void agg_kernel(const u16* __restrict__ h,
                                                  const u32* __restrict__ rs,
                                                  const u32* __restrict__ ep,
                                                  const float* __restrict__ emb,
                                                  u16* __restrict__ agg) {
    __shared__ float semb[8 * HID];
    int tid = threadIdx.x;
    ((float4*)semb)[tid] = ((const float4*)emb)[tid];
    __syncthreads();
    int wave = tid >> 6, lane = tid & 63;
    int node = blockIdx.x * 4 + wave;
    u32 s0 = rs[node], s1 = rs[node + 1];
    const u32* h32 = (const u32*)h;
    const float2* e2 = (const float2*)semb;
    float ax = 0.f, ay = 0.f;
    u32 j = s0;
    for (; j + 8 <= s1; j += 8) {
        u32 p[8];
#pragma unroll
        for (int t = 0; t < 8; ++t) p[t] = ep[j + t];
        u32 hv[8];
#pragma unroll
        for (int t = 0; t < 8; ++t) hv[t] = h32[(size_t)(p[t] & 0xFFFFFu) * 64 + lane];
        float2 ev[8];
#pragma unroll
        for (int t = 0; t < 8; ++t) ev[t] = e2[(p[t] >> 20) * 64 + lane];
#pragma unroll
        for (int t = 0; t < 8; ++t) {
            ax += fmaxf(__uint_as_float(hv[t] << 16) + ev[t].x, 0.f);
            ay += fmaxf(__uint_as_float(hv[t] & 0xFFFF0000u) + ev[t].y, 0.f);
        }
    }
    if (j + 4 <= s1) {
        u32 p[4];
#pragma unroll
        for (int t = 0; t < 4; ++t) p[t] = ep[j + t];
        u32 hv[4];
#pragma unroll
        for (int t = 0; t < 4; ++t) hv[t] = h32[(size_t)(p[t] & 0xFFFFFu) * 64 + lane];
        float2 ev[4];
#pragma unroll
        for (int t = 0; t < 4; ++t) ev[t] = e2[(p[t] >> 20) * 64 + lane];
#pragma unroll
        for (int t = 0; t < 4; ++t) {
            ax += fmaxf(__uint_as_float(hv[t] << 16) + ev[t].x, 0.f);
            ay += fmaxf(__uint_as_float(hv[t] & 0xFFFF0000u) + ev[t].y, 0.f);
        }
        j += 4;
    }
    for (; j < s1; j++) {
        u32 p = ep[j];
        u32 hv = h32[(size_t)(p & 0xFFFFFu) * 64 + lane];
        float2 ev = e2[(p >> 20) * 64 + lane];
        ax += fmaxf(__uint_as_float(hv << 16) + ev.x, 0.f);
        ay += fmaxf(__uint_as_float(hv & 0xFFFF0000u) + ev.y, 0.f);
    }
    ((u32*)agg)[(size_t)node * 64 + lane] = pack2(ax, ay);
}

// ---------------- MFMA MLP (unchanged from R4, verified) ----------------

__device__ inline void stageWt(char* sW, const uint4* __restrict__ Wt4, int tid) {
#pragma unroll
    for (int it = 0; it < 8; ++it) {
        int u = it * 256 + tid;
        int n = u >> 4, c = u & 15;
        uint4 v = Wt4[(size_t)n * 16 + c];
        *(uint4*)(sW + n * 256 + ((c * 16) ^ ((n & 15) << 4))) = v;
    }
}

template <int NL, int MODE, bool OUTB>
__global__ __launch_bounds__(256, 2) void mlp_mfma(
    const void* __restrict__ inp, const u16* __restrict__ aggb,
    const float* __restrict__ epsp, void* __restrict__ outp,
    const u32* __restrict__ Wt0, const float* __restrict__ b0,
    const u32* __restrict__ Wt1, const float* __restrict__ b1,
    const u32* __restrict__ Wt2, const float* __restrict__ b2) {
    __shared__ __align__(16) char sA[128 * 256];
    __shared__ __align__(16) char sW[128 * 256];
    int tid = threadIdx.x;
    int row0 = blockIdx.x * 128;

    if (MODE == 0) {
        const float* x = (const float*)inp;
#pragma unroll
        for (int it = 0; it < 16; ++it) {
            int idx = it * 256 + tid;
            int r = idx >> 5, c4 = (idx & 31) * 4;
            int grow = row0 + r;
            uint2 pk = make_uint2(0u, 0u);
            if (grow < NN) {
                float4 v = *(const float4*)&x[(size_t)grow * HID + c4];
                pk.x = pack2(v.x, v.y);
                pk.y = pack2(v.z, v.w);
            }
            *(uint2*)(sA + r * 256 + ((c4 * 2) ^ ((r & 15) << 4))) = pk;
        }
    } else {
        const u16* hin = (const u16*)inp;
        float eps = 1.0f + epsp[0];
#pragma unroll
        for (int it = 0; it < 16; ++it) {
            int idx = it * 256 + tid;
            int r = idx >> 5, c4 = (idx & 31) * 4;
            int grow = row0 + r;
            uint2 pk = make_uint2(0u, 0u);
            if (grow < NN) {
                ushort4 hv = *(const ushort4*)&hin[(size_t)grow * HID + c4];
                ushort4 gv = *(const ushort4*)&aggb[(size_t)grow * HID + c4];
                pk.x = pack2(eps * b2f(hv.x) + b2f(gv.x), eps * b2f(hv.y) + b2f(gv.y));
                pk.y = pack2(eps * b2f(hv.z) + b2f(gv.z), eps * b2f(hv.w) + b2f(gv.w));
            }
            *(uint2*)(sA + r * 256 + ((c4 * 2) ^ ((r & 15) << 4))) = pk;
        }
    }
    stageWt(sW, (const uint4*)Wt0, tid);
    __syncthreads();

    int lane = tid & 63, w = tid >> 6;
    int lo5 = lane & 31, hi = lane >> 5;
    int swzkey = (lo5 & 15) << 4;

#pragma unroll 1
    for (int l = 0; l < NL; ++l) {
        const float* bl = (l == 0) ? b0 : ((l == 1) ? b1 : b2);
        f32x16 acc[4];
#pragma unroll
        for (int nf = 0; nf < 4; ++nf) {
            float bv = bl[nf * 32 + lo5];
#pragma unroll
            for (int i = 0; i < 16; ++i) acc[nf][i] = bv;
        }
#pragma unroll
        for (int kc = 0; kc < 8; ++kc) {
            int koff = kc * 32 + hi * 16;
            bf16x8 a = *(const bf16x8*)(sA + (32 * w + lo5) * 256 + (koff ^ swzkey));
#pragma unroll
            for (int nf = 0; nf < 4; ++nf) {
                bf16x8 bb = *(const bf16x8*)(sW + (nf * 32 + lo5) * 256 + (koff ^ swzkey));
                acc[nf] = __builtin_amdgcn_mfma_f32_32x32x16_bf16(a, bb, acc[nf], 0, 0, 0);
            }
        }
        if (l + 1 < NL) {
            __syncthreads();
            stageWt(sW, (const uint4*)((l == 0) ? Wt1 : Wt2), tid);
#pragma unroll
            for (int nf = 0; nf < 4; ++nf) {
#pragma unroll
                for (int reg = 0; reg < 16; ++reg) {
                    int r32 = (reg & 3) + 8 * (reg >> 2) + 4 * hi;
                    int col = nf * 32 + lo5;
                    float v = fmaxf(acc[nf][reg], 0.f);
                    *(u16*)(sA + (32 * w + r32) * 256 + ((col * 2) ^ ((r32 & 15) << 4))) =
                        __builtin_bit_cast(u16, (__bf16)v);
                }
            }
            __syncthreads();
        } else {
#pragma unroll
            for (int nf = 0; nf < 4; ++nf) {
#pragma unroll
                for (int reg = 0; reg < 16; ++reg) {
                    int r32 = (reg & 3) + 8 * (reg >> 2) + 4 * hi;
                    int grow = row0 + 32 * w + r32;
                    int col = nf * 32 + lo5;
                    float v = fmaxf(acc[nf][reg], 0.f);
                    if (grow < NN) {
                        if (OUTB)
                            ((u16*)outp)[(size_t)grow * HID + col] =
                                __builtin_bit_cast(u16, (__bf16)v);
                        else
                            ((float*)outp)[(size_t)grow * HID + col] = v;
                    }
                }
            }
        }
    }
}

// ---------------- launch ----------------

extern "C" void kernel_launch(void* const* d_in, const int* in_sizes, int n_in,
                              void* d_out, int out_size, void* d_ws, size_t ws_size,
                              hipStream_t stream) {
    const float* x    = (const float*)d_in[0];
    const int*   ei   = (const int*)d_in[1];
    const int*   ea   = (const int*)d_in[2];
    const float* Wx   = (const float*)d_in[3];
    const float* bx   = (const float*)d_in[4];
    const float* emb  = (const float*)d_in[5];
    const float* eps1 = (const float*)d_in[6];
    const float* eps2 = (const float*)d_in[7];
    const float* W1a = (const float*)d_in[8],  *b1a = (const float*)d_in[9];
    const float* W1b = (const float*)d_in[10], *b1b = (const float*)d_in[11];
    const float* W1c = (const float*)d_in[12], *b1c = (const float*)d_in[13];
    const float* W2a = (const float*)d_in[14], *b2a = (const float*)d_in[15];
    const float* W2b = (const float*)d_in[16], *b2b = (const float*)d_in[17];
    const float* W2c = (const float*)d_in[18], *b2c = (const float*)d_in[19];
    float* out = (float*)d_out;

    const int* srcp = ei;
    const int* dstp = ei + NE;

    char* ws = (char*)d_ws;
    u16* h16   = (u16*)ws;                                          // 25.6MB
    size_t off = (size_t)NNP * HID * 2;
    u16* agg16 = (u16*)(ws + off); off += (size_t)NNP * HID * 2;    // 25.6MB
    u32* binned = (u32*)agg16;      // alias: binned only live before agg writes
    u32* rs   = (u32*)(ws + off); off += 400032;                    // NN+1 u32
    u32* bcnt = (u32*)(ws + off); off += 256 * 4;
    u32* boff = (u32*)(ws + off); off += 256 * 4;
    u32* bcur = (u32*)(ws + off); off += 256 * 4;
    u32* ep   = (u32*)(ws + off); off += (size_t)NE * 4;            // 6.4MB
    u32* Wt   = (u32*)(ws + off); off += 7 * 8192 * 4;

    hipMemsetAsync(bcnt, 0, 256 * 4, stream);

    // pre-transpose all 7 weight matrices to bf16 Wt[n][k]
    wt_kernel<<<14, 256, 0, stream>>>(Wx, W1a, W1b, W1c, W2a, W2b, W2c, Wt);

    // h = relu(x @ Wx + bx)  -> bf16
    mlp_mfma<1, 0, true><<<NNP / 128, 256, 0, stream>>>(
        x, nullptr, nullptr, h16, Wt, bx, nullptr, nullptr, nullptr, nullptr);

    // CSR build: two-level counting sort
    bincount_kernel<<<NBB, 256, 0, stream>>>(dstp, bcnt);
    bucketscan_kernel<<<1, 256, 0, stream>>>(bcnt, boff, bcur);
    binscatter_kernel<<<NBB, 256, 0, stream>>>(srcp, dstp, ea, bcur, binned);
    bucketcsr_kernel<<<NBUK, 256, 0, stream>>>(boff, binned, rs, ep);

    // layer 1
    agg_kernel<<<NN / 4, 256, 0, stream>>>(h16, rs, ep, emb, agg16);
    mlp_mfma<3, 1, true><<<NNP / 128, 256, 0, stream>>>(
        h16, agg16, eps1, h16, Wt + 8192, b1a, Wt + 2 * 8192, b1b, Wt + 3 * 8192, b1c);

    // layer 2 -> d_out fp32
    agg_kernel<<<NN / 4, 256, 0, stream>>>(h16, rs, ep, emb, agg16);
    mlp_mfma<3, 1, false><<<NNP / 128, 256, 0, stream>>>(
        h16, agg16, eps2, out, Wt + 4 * 8192, b2a, Wt + 5 * 8192, b2b, Wt + 6 * 8192, b2c);
}